// Round 11
// baseline (279.365 us; speedup 1.0000x reference)
//
#include <hip/hip_runtime.h>
#include <hip/hip_bf16.h>

#define DM 1024
#define NH 16
#define AD 64
#define BB 2
#define SS 2048
#define LOG2E 1.44269504f

typedef float f32x4 __attribute__((ext_vector_type(4)));
typedef short bf16x8 __attribute__((ext_vector_type(8)));
typedef unsigned short u16;
typedef unsigned int u32;
typedef u16 u16x4 __attribute__((ext_vector_type(4)));
typedef u16 u16x8 __attribute__((ext_vector_type(8)));
typedef u32 u32x4 __attribute__((ext_vector_type(4)));

static __device__ __forceinline__ u16 f2bf(float f) {
  unsigned u = __builtin_bit_cast(unsigned, f);
  u += 0x7fffu + ((u >> 16) & 1u);  // round-to-nearest-even
  return (u16)(u >> 16);
}

// raw v_exp_f32: args here are always in [-40, 0] -> identical to exp2f, minus ocml fixups
#if __has_builtin(__builtin_amdgcn_exp2f)
#define FEXP2(x) __builtin_amdgcn_exp2f(x)
#else
#define FEXP2(x) exp2f(x)
#endif

#define MFMA16(a, b, c) __builtin_amdgcn_mfma_f32_16x16x32_bf16((a), (b), (c), 0, 0, 0)

// async global->LDS, 16B per lane (LDS dest linear: base + 16*lane)
static __device__ __forceinline__ void ld_lds16(const void* g, void* l) {
  __builtin_amdgcn_global_load_lds((const __attribute__((address_space(1))) u32*)g,
                                   (__attribute__((address_space(3))) u32*)l, 16, 0, 0);
}

// counted waits + raw barrier (T3/T4: never drain prefetch/stores to 0 in-loop)
#define WAITV(N)                                             \
  do {                                                       \
    asm volatile("s_waitcnt vmcnt(" #N ")" ::: "memory");    \
    __builtin_amdgcn_sched_barrier(0);                       \
  } while (0)
#define WAITL0()                                             \
  do {                                                       \
    asm volatile("s_waitcnt lgkmcnt(0)" ::: "memory");       \
    __builtin_amdgcn_sched_barrier(0);                       \
  } while (0)
#define BAR() __builtin_amdgcn_s_barrier()

// swizzled b128 read of 16B piece P (0..7) from a row of a [R][64] u16 tile staged
// with pre-swizzled source: LDS[row][p] holds global piece (p ^ (row&7)).
#define KFRAG(buf, row, P) (*(const bf16x8*)(&(buf)[(row) * 64 + ((((P) ^ ((row) & 7))) << 3)]))
// swizzled b64 read: quad P (0..7), 8-byte half hh (0/1)
#define V64(buf, row, P, hh) \
  (*(const u16x4*)(&(buf)[(row) * 64 + ((((P) ^ ((row) & 7))) << 3) + (hh) * 4]))

// pack 2 f32 -> 2 bf16 (RNE) in one instruction
static __device__ __forceinline__ u32 cvt_pk_bf16(float lo, float hi) {
  u32 r;
  asm("v_cvt_pk_bf16_f32 %0, %1, %2" : "=v"(r) : "v"(lo), "v"(hi));
  return r;
}

// ---------------- merged prep: cast q/k/v + transpose-cast Wq/Wk/Wv/Wo, ONE launch -------
// blocks [0,2100): cast3 (tensor = id/700); [2100,2868): tcast W qkv; [2868,3124): tcast Wo.
__global__ __launch_bounds__(256, 4) void prep_kernel(const float* __restrict__ q,
                                                      const float* __restrict__ k,
                                                      const float* __restrict__ v,
                                                      const float* __restrict__ Wq,
                                                      const float* __restrict__ Wk,
                                                      const float* __restrict__ Wv,
                                                      const float* __restrict__ Wo,
                                                      u16* __restrict__ xq,
                                                      u16* __restrict__ WqT,
                                                      u16* __restrict__ WoT) {
  __shared__ float T[64][65];
  const long NX = (long)BB * SS * DM;
  int id = blockIdx.x;
  int tid = threadIdx.x;
  if (id < 2100) {
    int tensor = id / 700, xi = id - tensor * 700;
    const float* src = tensor == 0 ? q : tensor == 1 ? k : v;
    u16* dst = xq + (long)tensor * NX;
    int n8 = (int)(NX / 8);
    int stride = 700 * 256;
    for (int i = xi * 256 + tid; i < n8; i += stride) {
      const f32x4* p = (const f32x4*)src + 2 * (size_t)i;
      f32x4 a = p[0], b = p[1];
      u16x8 o;
      o[0] = f2bf(a[0]); o[1] = f2bf(a[1]); o[2] = f2bf(a[2]); o[3] = f2bf(a[3]);
      o[4] = f2bf(b[0]); o[5] = f2bf(b[1]); o[6] = f2bf(b[2]); o[7] = f2bf(b[3]);
      *((u16x8*)dst + i) = o;
    }
    return;
  }
  const float* src;
  u16* dstp;
  float scale;
  long bo;
  int R, C, r0, c0;
  if (id < 2868) {  // W qkv transpose: [h][1024][64] -> [h][64][1024]
    int flat = id - 2100;
    int x = flat & 15, z = flat >> 4;             // z in [0,48)
    int which = z >> 4, zz = z & 15;
    src = which == 0 ? Wq : which == 1 ? Wk : Wv;
    R = DM; C = AD;
    bo = (long)zz * R * C;
    dstp = WqT + (long)which * NH * R * C;
    scale = which == 0 ? (LOG2E / AD) : 1.0f;     // fold log2e/AD into WqT
    r0 = x * 64; c0 = 0;
  } else {  // Wo transpose: [1024][1024] -> [1024][1024]^T
    int flat = id - 2868;
    int x = flat & 15, yb = flat >> 4;
    src = Wo; dstp = WoT; scale = 1.0f;
    R = DM; C = DM; bo = 0;
    r0 = x * 64; c0 = yb * 64;
  }
  int cl = tid & 63, rl = tid >> 6;
#pragma unroll
  for (int i = 0; i < 16; i++) {
    int rr = rl + 4 * i;
    T[cl][rr] = src[bo + (long)(r0 + rr) * C + c0 + cl];
  }
  __syncthreads();
#pragma unroll
  for (int i = 0; i < 16; i++) {
    int cc = rl + 4 * i;
    dstp[bo + (long)(c0 + cc) * R + r0 + cl] = f2bf(T[cc][cl] * scale);
  }
}

// ---------------- merged QKV projection GEMM: 128x64 tile, dbuf LDS, counted waits -------
// which = blockIdx.z picks (X, WT, out-layout). C[s,col] = sum_k X[b][s][k]*WT[col][k].
__global__ __launch_bounds__(256, 3) void qkvproj_kernel(const u16* __restrict__ X0,
                                                         const u16* __restrict__ WT0,
                                                         u16* __restrict__ out0) {
  __shared__ u16 Ab[2][128 * 64];
  __shared__ u16 Bb[2][64 * 64];
  const long NX = (long)BB * SS * DM;
  const long NW = (long)NH * DM * AD;
  int which = blockIdx.z;
  int sg0 = blockIdx.x * 128;
  int b = sg0 >> 11, s0 = sg0 & (SS - 1);
  int h = blockIdx.y;
  int tid = threadIdx.x, w = tid >> 6, lane = tid & 63, g = lane >> 4, li = lane & 15;
  const u16* xb = X0 + (long)which * NX + ((long)b * SS + s0) * DM;
  const u16* wb = WT0 + (long)which * NW + (long)h * 64 * DM;
  u16* outp = out0 + (long)which * NX;

  const u16* asrc[4];
  u16* adst[2][4];
#pragma unroll
  for (int i = 0; i < 4; i++) {
    int cc = i * 256 + tid;
    int row = cc >> 3, sp = (cc ^ (row & 7)) & 7;
    asrc[i] = xb + (long)row * DM + sp * 8;
    adst[0][i] = &Ab[0][cc * 8];
    adst[1][i] = &Ab[1][cc * 8];
  }
  const u16* bsrc[2];
  u16* bdst[2][2];
#pragma unroll
  for (int i = 0; i < 2; i++) {
    int cc = i * 256 + tid;
    int row = cc >> 3, sp = (cc ^ (row & 7)) & 7;
    bsrc[i] = wb + (long)row * DM + sp * 8;
    bdst[0][i] = &Bb[0][cc * 8];
    bdst[1][i] = &Bb[1][cc * 8];
  }

#pragma unroll
  for (int i = 0; i < 4; i++) ld_lds16(asrc[i], adst[0][i]);
#pragma unroll
  for (int i = 0; i < 2; i++) ld_lds16(bsrc[i], bdst[0][i]);

  f32x4 acc[2][4] = {};
  for (int kc = 0; kc < DM / 64; kc++) {
    int cur = kc & 1;
    if (kc + 1 < DM / 64) {
      int ko = (kc + 1) * 64;
#pragma unroll
      for (int i = 0; i < 4; i++) ld_lds16(asrc[i] + ko, adst[cur ^ 1][i]);
#pragma unroll
      for (int i = 0; i < 2; i++) ld_lds16(bsrc[i] + ko, bdst[cur ^ 1][i]);
      WAITV(6);
    } else {
      WAITV(0);
    }
    BAR();
    const u16* ab = Ab[cur];
    const u16* bb = Bb[cur];
    __builtin_amdgcn_s_setprio(1);
#pragma unroll
    for (int kk = 0; kk < 2; kk++) {
      bf16x8 bf[4];
#pragma unroll
      for (int j = 0; j < 4; j++) bf[j] = KFRAG(bb, j * 16 + li, kk * 4 + g);
#pragma unroll
      for (int mi = 0; mi < 2; mi++) {
        bf16x8 af = KFRAG(ab, w * 32 + mi * 16 + li, kk * 4 + g);
#pragma unroll
        for (int j = 0; j < 4; j++) acc[mi][j] = MFMA16(af, bf[j], acc[mi][j]);
      }
    }
    __builtin_amdgcn_s_setprio(0);
    WAITL0();
    BAR();
  }

  long obase = (long)h * (BB * SS * AD) + (long)b * (SS * AD);
#pragma unroll
  for (int mi = 0; mi < 2; mi++) {
    int sb = s0 + w * 32 + mi * 16 + 4 * g;
#pragma unroll
    for (int j = 0; j < 4; j++) {
      int e = j * 16 + li;
      if (which < 2) {
#pragma unroll
        for (int r = 0; r < 4; r++)
          outp[obase + (long)(sb + r) * AD + e] = f2bf(acc[mi][j][r]);
      } else {
        u16x4 vv;
#pragma unroll
        for (int r = 0; r < 4; r++) vv[r] = f2bf(acc[mi][j][r]);
        *(u16x4*)(outp + obase + (long)e * SS + sb) = vv;
      }
    }
  }
}

// ---------------- output projection: cat[4096][1024] bf16 x WoT -> out[4096][1024] f32 ----
__global__ __launch_bounds__(256, 3) void outproj_kernel(const u16* __restrict__ X,
                                                         const u16* __restrict__ WT,
                                                         float* __restrict__ out) {
  __shared__ u16 Ab[2][128 * 64];
  __shared__ u16 Bb[2][64 * 64];
  int sg0 = blockIdx.x * 128;
  int n0 = blockIdx.y * 64;
  int tid = threadIdx.x, w = tid >> 6, lane = tid & 63, g = lane >> 4, li = lane & 15;
  const u16* xb = X + (long)sg0 * DM;
  const u16* wb = WT + (long)n0 * DM;

  const u16* asrc[4];
  u16* adst[2][4];
#pragma unroll
  for (int i = 0; i < 4; i++) {
    int cc = i * 256 + tid;
    int row = cc >> 3, sp = (cc ^ (row & 7)) & 7;
    asrc[i] = xb + (long)row * DM + sp * 8;
    adst[0][i] = &Ab[0][cc * 8];
    adst[1][i] = &Ab[1][cc * 8];
  }
  const u16* bsrc[2];
  u16* bdst[2][2];
#pragma unroll
  for (int i = 0; i < 2; i++) {
    int cc = i * 256 + tid;
    int row = cc >> 3, sp = (cc ^ (row & 7)) & 7;
    bsrc[i] = wb + (long)row * DM + sp * 8;
    bdst[0][i] = &Bb[0][cc * 8];
    bdst[1][i] = &Bb[1][cc * 8];
  }

#pragma unroll
  for (int i = 0; i < 4; i++) ld_lds16(asrc[i], adst[0][i]);
#pragma unroll
  for (int i = 0; i < 2; i++) ld_lds16(bsrc[i], bdst[0][i]);

  f32x4 acc[2][4] = {};
  for (int kc = 0; kc < DM / 64; kc++) {
    int cur = kc & 1;
    if (kc + 1 < DM / 64) {
      int ko = (kc + 1) * 64;
#pragma unroll
      for (int i = 0; i < 4; i++) ld_lds16(asrc[i] + ko, adst[cur ^ 1][i]);
#pragma unroll
      for (int i = 0; i < 2; i++) ld_lds16(bsrc[i] + ko, bdst[cur ^ 1][i]);
      WAITV(6);
    } else {
      WAITV(0);
    }
    BAR();
    const u16* ab = Ab[cur];
    const u16* bb = Bb[cur];
    __builtin_amdgcn_s_setprio(1);
#pragma unroll
    for (int kk = 0; kk < 2; kk++) {
      bf16x8 bf[4];
#pragma unroll
      for (int j = 0; j < 4; j++) bf[j] = KFRAG(bb, j * 16 + li, kk * 4 + g);
#pragma unroll
      for (int mi = 0; mi < 2; mi++) {
        bf16x8 af = KFRAG(ab, w * 32 + mi * 16 + li, kk * 4 + g);
#pragma unroll
        for (int j = 0; j < 4; j++) acc[mi][j] = MFMA16(af, bf[j], acc[mi][j]);
      }
    }
    __builtin_amdgcn_s_setprio(0);
    WAITL0();
    BAR();
  }

#pragma unroll
  for (int mi = 0; mi < 2; mi++) {
    int sb = sg0 + w * 32 + mi * 16 + 4 * g;
#pragma unroll
    for (int j = 0; j < 4; j++) {
      int col = n0 + j * 16 + li;
#pragma unroll
      for (int r = 0; r < 4; r++) out[(long)(sb + r) * DM + col] = acc[mi][j][r];
    }
  }
}

// ---------------- fused attention: grid (hb=32, qblock=32), 256-thr blocks (4 waves) -----
// XCD locality: linear id fast-axis = hb -> all 32 q-blocks of one (h,b) on ONE XCD.
// sacc in log2 units (LOG2E/AD folded into WqT); no-max softmax (scores tiny, exact f32).
// Pass 1: PAIR-PROCESSED 4-slot pipeline — 2 chunks per barrier pair (32 barriers vs 64);
//         prefetch-after-compute into the just-freed slot pair; steady WAITV(4).
// Pass 2: -moff folded into MFMA C-init; raw v_exp_f32; plain stores; PV k-permuted.
__global__ __launch_bounds__(256, 4) void attn_kernel(const u16* __restrict__ qh,
                                                      const u16* __restrict__ kh,
                                                      const u16* __restrict__ vhT,
                                                      float* __restrict__ attn_out,
                                                      u16* __restrict__ cat) {
  __shared__ u16 Kb[2][64 * 64];
  __shared__ u16 Vb[2][64 * 64];
  int hb = blockIdx.x;          // fast axis -> XCD = hb%8
  int h = hb >> 1, b = hb & 1;  // hb = h*BB + b
  int tid = threadIdx.x;
  int w = tid >> 6, lane = tid & 63;
  int g = lane >> 4, li = lane & 15;
  long base = (long)hb * SS * AD;
  const u16* qhb = qh + base;
  const u16* khb = kh + base;
  const u16* vhb = vhT + base;
  int q0 = blockIdx.y * 64 + w * 16;

  // Q fragments (B-operand): lane(g,li) = Q^T[e=8g..][q=li]
  bf16x8 bq0 = *(const bf16x8*)(qhb + (q0 + li) * AD + 8 * g);
  bf16x8 bq1 = *(const bf16x8*)(qhb + (q0 + li) * AD + 32 + 8 * g);

  // staging: 2 pieces/thread: cc1 = tid (rows 0..31), cc2 = tid+256 (rows 32..63)
  int r1 = tid >> 3, p1 = (tid ^ (r1 & 7)) & 7;
  int r2 = (tid + 256) >> 3, p2 = ((tid + 256) ^ (r2 & 7)) & 7;
  const u16* ks1 = khb + (long)r1 * AD + p1 * 8;
  const u16* ks2 = khb + (long)r2 * AD + p2 * 8;
  const u16* vs1 = vhb + (long)r1 * SS + p1 * 8;
  const u16* vs2 = vhb + (long)r2 * SS + p2 * 8;
  u16* kd0a = &Kb[0][tid * 8]; u16* kd0b = &Kb[0][(tid + 256) * 8];
  u16* kd1a = &Kb[1][tid * 8]; u16* kd1b = &Kb[1][(tid + 256) * 8];
  u16* vd0a = &Vb[0][tid * 8]; u16* vd0b = &Vb[0][(tid + 256) * 8];
  u16* vd1a = &Vb[1][tid * 8]; u16* vd1b = &Vb[1][(tid + 256) * 8];

  // ===== pass 1: l = sum exp2(sacc); 4 slots, 2 chunks per barrier pair =====
  // chunk c -> slot pair ((c>>1)&1): 0 -> {Kb0,Kb1}, 1 -> {Vb0,Vb1}
  f32x4 l4 = {0.f, 0.f, 0.f, 0.f};
  ld_lds16(ks1, kd0a); ld_lds16(ks2, kd0b);
  ld_lds16(ks1 + 64 * AD, kd1a); ld_lds16(ks2 + 64 * AD, kd1b);
  ld_lds16(ks1 + 2 * 64 * AD, vd0a); ld_lds16(ks2 + 2 * 64 * AD, vd0b);
  ld_lds16(ks1 + 3 * 64 * AD, vd1a); ld_lds16(ks2 + 3 * 64 * AD, vd1b);
  for (int ci = 0; ci < 16; ci++) {  // pair ci = chunks 2ci, 2ci+1
    if (ci < 15) {
      WAITV(4);  // outstanding <= [L_cur(4), L_next(4)]; oldest 4 (= current pair) done
    } else {
      WAITV(0);
    }
    BAR();
    const u16* kbuf0 = (ci & 1) ? Vb[0] : Kb[0];
    const u16* kbuf1 = (ci & 1) ? Vb[1] : Kb[1];
#pragma unroll
    for (int u2 = 0; u2 < 2; u2++) {
      const u16* kb = u2 ? kbuf1 : kbuf0;
      f32x4 sacc[4] = {};
      __builtin_amdgcn_s_setprio(1);
#pragma unroll
      for (int mi = 0; mi < 4; mi++) {
        bf16x8 a0 = KFRAG(kb, mi * 16 + li, g);
        bf16x8 a1 = KFRAG(kb, mi * 16 + li, 4 + g);
        sacc[mi] = MFMA16(a0, bq0, sacc[mi]);
        sacc[mi] = MFMA16(a1, bq1, sacc[mi]);
      }
      __builtin_amdgcn_s_setprio(0);
#pragma unroll
      for (int c = 0; c < 4; c++)
#pragma unroll
        for (int r = 0; r < 4; r++) l4[r] += FEXP2(sacc[c][r]);
    }
    WAITL0();
    BAR();
    if (ci < 14) {  // prefetch chunks 2ci+4, 2ci+5 into the pair just computed
      int cn = 2 * ci + 4;
      u16* da = (ci & 1) ? vd0a : kd0a;
      u16* db = (ci & 1) ? vd0b : kd0b;
      u16* da2 = (ci & 1) ? vd1a : kd1a;
      u16* db2 = (ci & 1) ? vd1b : kd1b;
      ld_lds16(ks1 + (long)cn * 64 * AD, da);
      ld_lds16(ks2 + (long)cn * 64 * AD, db);
      ld_lds16(ks1 + (long)(cn + 1) * 64 * AD, da2);
      ld_lds16(ks2 + (long)(cn + 1) * 64 * AD, db2);
    }
  }
  float l_run = (l4[0] + l4[1]) + (l4[2] + l4[3]);
  // merge l across the 4 g-lanes holding the same q=li
  l_run += __shfl_xor(l_run, 16);
  l_run += __shfl_xor(l_run, 32);
  float moff = log2f(l_run);  // p = exp2(sacc - moff) is normalized softmax
  f32x4 minit = {-moff, -moff, -moff, -moff};  // lane's 16 S-values all share q=li

  // ================= pass 2: attn write + PV (round-8 proven scheme) =================
  ld_lds16(ks1, kd0a); ld_lds16(ks2, kd0b);
  ld_lds16(vs1, vd0a); ld_lds16(vs2, vd0b);
  f32x4 accv[4] = {};
  float* arow = attn_out + ((long)hb * SS + q0 + li) * SS;
  for (int ch2 = 0; ch2 < SS / 64; ch2 += 2) {
#pragma unroll
    for (int u = 0; u < 2; u++) {
      int ch = ch2 + u;
      u16* kpa = u ? kd0a : kd1a; u16* kpb = u ? kd0b : kd1b;
      u16* vpa = u ? vd0a : vd1a; u16* vpb = u ? vd0b : vd1b;
      if (ch + 1 < SS / 64) {
        ld_lds16(ks1 + (long)(ch + 1) * 64 * AD, kpa);
        ld_lds16(ks2 + (long)(ch + 1) * 64 * AD, kpb);
        ld_lds16(vs1 + (ch + 1) * 64, vpa);
        ld_lds16(vs2 + (ch + 1) * 64, vpb);
        if (ch == 0) {
          WAITV(4);  // queue: [KV0(4), KV1(4)] -> KV0 done
        } else {
          WAITV(8);  // queue: [KVc(4), S_{c-1}(4), KVn(4)] -> KVc done; stores fly
        }
      } else {
        WAITV(4);  // queue: [S_{c-2}(4), KVc(4), S_{c-1}(4)] -> KVc done
      }
      BAR();
      const u16* kb = Kb[u];
      const u16* vb = Vb[u];
      f32x4 sacc[4] = {minit, minit, minit, minit};  // C-init = -moff (free subtract)
      __builtin_amdgcn_s_setprio(1);
#pragma unroll
      for (int mi = 0; mi < 4; mi++) {
        bf16x8 a0 = KFRAG(kb, mi * 16 + li, g);
        bf16x8 a1 = KFRAG(kb, mi * 16 + li, 4 + g);
        sacc[mi] = MFMA16(a0, bq0, sacc[mi]);
        sacc[mi] = MFMA16(a1, bq1, sacc[mi]);
      }
      __builtin_amdgcn_s_setprio(0);
      // p = exp2(sacc): plain store (L2 write-combines); cvt_pk packs P for PV
      u32 pw[8];
#pragma unroll
      for (int c = 0; c < 4; c++) {
        f32x4 pv;
#pragma unroll
        for (int r = 0; r < 4; r++) pv[r] = FEXP2(sacc[c][r]);
        *(f32x4*)(arow + ch * 64 + c * 16 + 4 * g) = pv;
        pw[2 * c] = cvt_pk_bf16(pv[0], pv[1]);
        pw[2 * c + 1] = cvt_pk_bf16(pv[2], pv[3]);
      }
      // PV: k-step kk covers lane's own k = {32kk+16cc+4g+r}; A-frag = own packed p.
#pragma unroll
      for (int kk = 0; kk < 2; kk++) {
        u32x4 aw = {pw[4 * kk], pw[4 * kk + 1], pw[4 * kk + 2], pw[4 * kk + 3]};
        bf16x8 ap = __builtin_bit_cast(bf16x8, aw);
#pragma unroll
        for (int et = 0; et < 4; et++) {
          int row = et * 16 + li;  // e-row of V^T tile
          u16x4 b0 = V64(vb, row, 4 * kk + (g >> 1), g & 1);
          u16x4 b1 = V64(vb, row, 4 * kk + 2 + (g >> 1), g & 1);
          u16x8 ub = {b0[0], b0[1], b0[2], b0[3], b1[0], b1[1], b1[2], b1[3]};
          bf16x8 bv = __builtin_bit_cast(bf16x8, ub);
          accv[et] = MFMA16(ap, bv, accv[et]);
        }
      }
      WAITL0();
      BAR();
    }
  }

  // epilogue: att already normalized; lane(g,li) holds att[q=4g+r][e=et*16+li]
#pragma unroll
  for (int et = 0; et < 4; et++)
#pragma unroll
    for (int r = 0; r < 4; r++)
      cat[((long)b * SS + q0 + 4 * g + r) * DM + h * AD + et * 16 + li] = f2bf(accv[et][r]);
}

extern "C" void kernel_launch(void* const* d_in, const int* in_sizes, int n_in, void* d_out,
                              int out_size, void* d_ws, size_t ws_size, hipStream_t stream) {
  const float* q = (const float*)d_in[0];
  const float* k = (const float*)d_in[1];
  const float* v = (const float*)d_in[2];
  const float* Wq = (const float*)d_in[3];
  const float* Wk = (const float*)d_in[4];
  const float* Wv = (const float*)d_in[5];
  const float* Wo = (const float*)d_in[6];
  float* out = (float*)d_out;
  float* attn_out = out + (long)BB * SS * DM;

  const long NX = (long)BB * SS * DM;  // 4,194,304
  const long NW = (long)NH * DM * AD;  // 1,048,576
  u16* ws = (u16*)d_ws;
  u16* xq = ws;        // xq, xk, xv contiguous (prep + qkvproj rely on this)
  u16* xk = xq + NX;
  u16* xv = xk + NX;
  u16* WqT = xv + NX;  // WqT, WkT, WvT contiguous (prep + qkvproj rely on this)
  u16* WkT = WqT + NW;
  u16* WvT = WkT + NW;
  u16* WoT = WvT + NW;
  u16* qhw = WoT + (long)DM * DM;  // qhw, khw, vhw contiguous (qkvproj relies on this)
  u16* khw = qhw + NX;
  u16* vhw = khw + NX;
  u16* catw = vhw + NX;  // total ws use: 64 MiB

  (void)xk; (void)xv; (void)WkT; (void)WvT;

  // one prep launch: cast q/k/v -> bf16 + transpose-cast all weights
  prep_kernel<<<3124, 256, 0, stream>>>(q, k, v, Wq, Wk, Wv, Wo, xq, WqT, WoT);

  // merged Q/K/V projections: grid 32 x 16 x 3 = 1536 blocks
  qkvproj_kernel<<<dim3(BB * SS / 128, NH, 3), 256, 0, stream>>>(xq, WqT, qhw);

  // attention: grid (hb=32, qblock=32) -> XCD-local K/V
  attn_kernel<<<dim3(NH * BB, SS / 64), 256, 0, stream>>>(qhw, khw, vhw, attn_out, catw);

  // out[b][s][d] = cat @ Wo : grid 32 x 16 = 512 blocks
  outproj_kernel<<<dim3(BB * SS / 128, DM / 64), 256, 0, stream>>>(catw, WoT, out);
}

// Round 13
// 258.872 us; speedup vs baseline: 1.0792x; 1.0792x over previous
//
#include <hip/hip_runtime.h>
#include <hip/hip_bf16.h>

#define DM 1024
#define NH 16
#define AD 64
#define BB 2
#define SS 2048
#define LOG2E 1.44269504f

typedef float f32x4 __attribute__((ext_vector_type(4)));
typedef short bf16x8 __attribute__((ext_vector_type(8)));
typedef unsigned short u16;
typedef unsigned int u32;
typedef u16 u16x4 __attribute__((ext_vector_type(4)));
typedef u16 u16x8 __attribute__((ext_vector_type(8)));
typedef u32 u32x4 __attribute__((ext_vector_type(4)));

static __device__ __forceinline__ u16 f2bf(float f) {
  unsigned u = __builtin_bit_cast(unsigned, f);
  u += 0x7fffu + ((u >> 16) & 1u);  // round-to-nearest-even
  return (u16)(u >> 16);
}

#define MFMA16(a, b, c) __builtin_amdgcn_mfma_f32_16x16x32_bf16((a), (b), (c), 0, 0, 0)

// async global->LDS, 16B per lane (LDS dest linear: base + 16*lane)
static __device__ __forceinline__ void ld_lds16(const void* g, void* l) {
  __builtin_amdgcn_global_load_lds((const __attribute__((address_space(1))) u32*)g,
                                   (__attribute__((address_space(3))) u32*)l, 16, 0, 0);
}

// counted waits + raw barrier (T3/T4: never drain prefetch/stores to 0 in-loop)
#define WAITV(N)                                             \
  do {                                                       \
    asm volatile("s_waitcnt vmcnt(" #N ")" ::: "memory");    \
    __builtin_amdgcn_sched_barrier(0);                       \
  } while (0)
#define WAITL0()                                             \
  do {                                                       \
    asm volatile("s_waitcnt lgkmcnt(0)" ::: "memory");       \
    __builtin_amdgcn_sched_barrier(0);                       \
  } while (0)
#define BAR() __builtin_amdgcn_s_barrier()

// swizzled b128 read of 16B piece P (0..7) from a row of a [R][64] u16 tile staged
// with pre-swizzled source: LDS[row][p] holds global piece (p ^ (row&7)).
#define KFRAG(buf, row, P) (*(const bf16x8*)(&(buf)[(row) * 64 + ((((P) ^ ((row) & 7))) << 3)]))
// swizzled b64 read: quad P (0..7), 8-byte half hh (0/1)
#define V64(buf, row, P, hh) \
  (*(const u16x4*)(&(buf)[(row) * 64 + ((((P) ^ ((row) & 7))) << 3) + (hh) * 4]))

// ---------------- fp32 -> bf16 cast of q,k,v in one launch ----------------
__global__ __launch_bounds__(256, 4) void cast3_kernel(const float* __restrict__ s0,
                                                       const float* __restrict__ s1,
                                                       const float* __restrict__ s2,
                                                       u16* __restrict__ d0, u16* __restrict__ d1,
                                                       u16* __restrict__ d2, int n8) {
  const float* src = blockIdx.y == 0 ? s0 : blockIdx.y == 1 ? s1 : s2;
  u16* dst = blockIdx.y == 0 ? d0 : blockIdx.y == 1 ? d1 : d2;
  int i = blockIdx.x * blockDim.x + threadIdx.x;
  int stride = gridDim.x * blockDim.x;
  for (; i < n8; i += stride) {
    const f32x4* p = (const f32x4*)src + 2 * (size_t)i;
    f32x4 a = p[0], b = p[1];
    u16x8 o;
    o[0] = f2bf(a[0]); o[1] = f2bf(a[1]); o[2] = f2bf(a[2]); o[3] = f2bf(a[3]);
    o[4] = f2bf(b[0]); o[5] = f2bf(b[1]); o[6] = f2bf(b[2]); o[7] = f2bf(b[3]);
    *((u16x8*)dst + i) = o;
  }
}

// ---------------- LDS-tiled transpose+cast ----------------
// MODE 0: one src [z][R][C]; MODE 1: three srcs (Wq/Wk/Wv), z/16 selects, scale on z<16.
template <int MODE>
__global__ __launch_bounds__(256, 4) void tcast_kernel(const float* __restrict__ s0,
                                                       const float* __restrict__ s1,
                                                       const float* __restrict__ s2,
                                                       u16* __restrict__ dst, int R, int C,
                                                       float scale0) {
  __shared__ float T[64][65];
  const float* src;
  u16* dstp;
  float scale;
  long bo;
  if (MODE == 0) {
    src = s0; bo = (long)blockIdx.z * R * C; dstp = dst; scale = scale0;
  } else {
    int which = blockIdx.z >> 4, zz = blockIdx.z & 15;
    src = which == 0 ? s0 : which == 1 ? s1 : s2;
    bo = (long)zz * R * C;
    dstp = dst + (long)which * NH * R * C;
    scale = which == 0 ? scale0 : 1.0f;
  }
  int r0 = blockIdx.x * 64, c0 = blockIdx.y * 64;
  int cl = threadIdx.x & 63, rl = threadIdx.x >> 6;
#pragma unroll
  for (int i = 0; i < 16; i++) {
    int rr = rl + 4 * i;
    T[cl][rr] = src[bo + (long)(r0 + rr) * C + c0 + cl];
  }
  __syncthreads();
#pragma unroll
  for (int i = 0; i < 16; i++) {
    int cc = rl + 4 * i;
    dstp[bo + (long)(c0 + cc) * R + r0 + cl] = f2bf(T[cc][cl] * scale);
  }
}

// ---------------- merged QKV projection GEMM: 128x64 tile, dbuf LDS, counted waits -------
// which = blockIdx.z picks (X, WT, out-layout). C[s,col] = sum_k X[b][s][k]*WT[col][k].
__global__ __launch_bounds__(256, 3) void qkvproj_kernel(const u16* __restrict__ X0,
                                                         const u16* __restrict__ WT0,
                                                         u16* __restrict__ out0) {
  __shared__ u16 Ab[2][128 * 64];
  __shared__ u16 Bb[2][64 * 64];
  const long NX = (long)BB * SS * DM;
  const long NW = (long)NH * DM * AD;
  int which = blockIdx.z;
  int sg0 = blockIdx.x * 128;
  int b = sg0 >> 11, s0 = sg0 & (SS - 1);
  int h = blockIdx.y;
  int tid = threadIdx.x, w = tid >> 6, lane = tid & 63, g = lane >> 4, li = lane & 15;
  const u16* xb = X0 + (long)which * NX + ((long)b * SS + s0) * DM;
  const u16* wb = WT0 + (long)which * NW + (long)h * 64 * DM;
  u16* outp = out0 + (long)which * NX;

  const u16* asrc[4];
  u16* adst[2][4];
#pragma unroll
  for (int i = 0; i < 4; i++) {
    int cc = i * 256 + tid;
    int row = cc >> 3, sp = (cc ^ (row & 7)) & 7;
    asrc[i] = xb + (long)row * DM + sp * 8;
    adst[0][i] = &Ab[0][cc * 8];
    adst[1][i] = &Ab[1][cc * 8];
  }
  const u16* bsrc[2];
  u16* bdst[2][2];
#pragma unroll
  for (int i = 0; i < 2; i++) {
    int cc = i * 256 + tid;
    int row = cc >> 3, sp = (cc ^ (row & 7)) & 7;
    bsrc[i] = wb + (long)row * DM + sp * 8;
    bdst[0][i] = &Bb[0][cc * 8];
    bdst[1][i] = &Bb[1][cc * 8];
  }

#pragma unroll
  for (int i = 0; i < 4; i++) ld_lds16(asrc[i], adst[0][i]);
#pragma unroll
  for (int i = 0; i < 2; i++) ld_lds16(bsrc[i], bdst[0][i]);

  f32x4 acc[2][4] = {};
  for (int kc = 0; kc < DM / 64; kc++) {
    int cur = kc & 1;
    if (kc + 1 < DM / 64) {
      int ko = (kc + 1) * 64;
#pragma unroll
      for (int i = 0; i < 4; i++) ld_lds16(asrc[i] + ko, adst[cur ^ 1][i]);
#pragma unroll
      for (int i = 0; i < 2; i++) ld_lds16(bsrc[i] + ko, bdst[cur ^ 1][i]);
      WAITV(6);
    } else {
      WAITV(0);
    }
    BAR();
    const u16* ab = Ab[cur];
    const u16* bb = Bb[cur];
    __builtin_amdgcn_s_setprio(1);
#pragma unroll
    for (int kk = 0; kk < 2; kk++) {
      bf16x8 bf[4];
#pragma unroll
      for (int j = 0; j < 4; j++) bf[j] = KFRAG(bb, j * 16 + li, kk * 4 + g);
#pragma unroll
      for (int mi = 0; mi < 2; mi++) {
        bf16x8 af = KFRAG(ab, w * 32 + mi * 16 + li, kk * 4 + g);
#pragma unroll
        for (int j = 0; j < 4; j++) acc[mi][j] = MFMA16(af, bf[j], acc[mi][j]);
      }
    }
    __builtin_amdgcn_s_setprio(0);
    WAITL0();
    BAR();
  }

  long obase = (long)h * (BB * SS * AD) + (long)b * (SS * AD);
#pragma unroll
  for (int mi = 0; mi < 2; mi++) {
    int sb = s0 + w * 32 + mi * 16 + 4 * g;
#pragma unroll
    for (int j = 0; j < 4; j++) {
      int e = j * 16 + li;
      if (which < 2) {
#pragma unroll
        for (int r = 0; r < 4; r++)
          outp[obase + (long)(sb + r) * AD + e] = f2bf(acc[mi][j][r]);
      } else {
        u16x4 vv;
#pragma unroll
        for (int r = 0; r < 4; r++) vv[r] = f2bf(acc[mi][j][r]);
        *(u16x4*)(outp + obase + (long)e * SS + sb) = vv;
      }
    }
  }
}

// ---------------- output projection: cat[4096][1024] bf16 x WoT -> out[4096][1024] f32 ----
__global__ __launch_bounds__(256, 3) void outproj_kernel(const u16* __restrict__ X,
                                                         const u16* __restrict__ WT,
                                                         float* __restrict__ out) {
  __shared__ u16 Ab[2][128 * 64];
  __shared__ u16 Bb[2][64 * 64];
  int sg0 = blockIdx.x * 128;
  int n0 = blockIdx.y * 64;
  int tid = threadIdx.x, w = tid >> 6, lane = tid & 63, g = lane >> 4, li = lane & 15;
  const u16* xb = X + (long)sg0 * DM;
  const u16* wb = WT + (long)n0 * DM;

  const u16* asrc[4];
  u16* adst[2][4];
#pragma unroll
  for (int i = 0; i < 4; i++) {
    int cc = i * 256 + tid;
    int row = cc >> 3, sp = (cc ^ (row & 7)) & 7;
    asrc[i] = xb + (long)row * DM + sp * 8;
    adst[0][i] = &Ab[0][cc * 8];
    adst[1][i] = &Ab[1][cc * 8];
  }
  const u16* bsrc[2];
  u16* bdst[2][2];
#pragma unroll
  for (int i = 0; i < 2; i++) {
    int cc = i * 256 + tid;
    int row = cc >> 3, sp = (cc ^ (row & 7)) & 7;
    bsrc[i] = wb + (long)row * DM + sp * 8;
    bdst[0][i] = &Bb[0][cc * 8];
    bdst[1][i] = &Bb[1][cc * 8];
  }

#pragma unroll
  for (int i = 0; i < 4; i++) ld_lds16(asrc[i], adst[0][i]);
#pragma unroll
  for (int i = 0; i < 2; i++) ld_lds16(bsrc[i], bdst[0][i]);

  f32x4 acc[2][4] = {};
  for (int kc = 0; kc < DM / 64; kc++) {
    int cur = kc & 1;
    if (kc + 1 < DM / 64) {
      int ko = (kc + 1) * 64;
#pragma unroll
      for (int i = 0; i < 4; i++) ld_lds16(asrc[i] + ko, adst[cur ^ 1][i]);
#pragma unroll
      for (int i = 0; i < 2; i++) ld_lds16(bsrc[i] + ko, bdst[cur ^ 1][i]);
      WAITV(6);
    } else {
      WAITV(0);
    }
    BAR();
    const u16* ab = Ab[cur];
    const u16* bb = Bb[cur];
    __builtin_amdgcn_s_setprio(1);
#pragma unroll
    for (int kk = 0; kk < 2; kk++) {
      bf16x8 bf[4];
#pragma unroll
      for (int j = 0; j < 4; j++) bf[j] = KFRAG(bb, j * 16 + li, kk * 4 + g);
#pragma unroll
      for (int mi = 0; mi < 2; mi++) {
        bf16x8 af = KFRAG(ab, w * 32 + mi * 16 + li, kk * 4 + g);
#pragma unroll
        for (int j = 0; j < 4; j++) acc[mi][j] = MFMA16(af, bf[j], acc[mi][j]);
      }
    }
    __builtin_amdgcn_s_setprio(0);
    WAITL0();
    BAR();
  }

#pragma unroll
  for (int mi = 0; mi < 2; mi++) {
    int sb = sg0 + w * 32 + mi * 16 + 4 * g;
#pragma unroll
    for (int j = 0; j < 4; j++) {
      int col = n0 + j * 16 + li;
#pragma unroll
      for (int r = 0; r < 4; r++) out[(long)(sb + r) * DM + col] = acc[mi][j][r];
    }
  }
}

// ---------------- fused attention: 256-thr blocks (4 waves), q-tile 64, grid 1024 -------
// 4 blocks/CU: each barrier couples only 4 waves; 3 other resident blocks hide the stall.
// sacc in log2 units (LOG2E/AD folded into WqT); no-max softmax (scores tiny, exact f32).
// Pass 1: 4-deep K prefetch via slots {Kb0,Kb1,Vb0,Vb1}; l = sum exp2(s).
// Pass 2: K+V 2-deep dbuf; p = exp2(s - log2 l); nt attn stores; PV k-permuted.
__global__ __launch_bounds__(256, 4) void attn_kernel(const u16* __restrict__ qh,
                                                      const u16* __restrict__ kh,
                                                      const u16* __restrict__ vhT,
                                                      float* __restrict__ attn_out,
                                                      u16* __restrict__ cat) {
  __shared__ u16 Kb[2][64 * 64];
  __shared__ u16 Vb[2][64 * 64];
  int h = blockIdx.y, b = blockIdx.z;
  int hb = h * BB + b;
  int tid = threadIdx.x;
  int w = tid >> 6, lane = tid & 63;
  int g = lane >> 4, li = lane & 15;
  long base = (long)hb * SS * AD;
  const u16* qhb = qh + base;
  const u16* khb = kh + base;
  const u16* vhb = vhT + base;
  int q0 = blockIdx.x * 64 + w * 16;

  // Q fragments (B-operand): lane(g,li) = Q^T[e=8g..][q=li]
  bf16x8 bq0 = *(const bf16x8*)(qhb + (q0 + li) * AD + 8 * g);
  bf16x8 bq1 = *(const bf16x8*)(qhb + (q0 + li) * AD + 32 + 8 * g);

  // staging: 2 pieces/thread: cc1 = tid (rows 0..31), cc2 = tid+256 (rows 32..63)
  int r1 = tid >> 3, p1 = (tid ^ (r1 & 7)) & 7;
  int r2 = (tid + 256) >> 3, p2 = ((tid + 256) ^ (r2 & 7)) & 7;
  const u16* ks1 = khb + (long)r1 * AD + p1 * 8;
  const u16* ks2 = khb + (long)r2 * AD + p2 * 8;
  const u16* vs1 = vhb + (long)r1 * SS + p1 * 8;
  const u16* vs2 = vhb + (long)r2 * SS + p2 * 8;
  u16* kd0a = &Kb[0][tid * 8]; u16* kd0b = &Kb[0][(tid + 256) * 8];
  u16* kd1a = &Kb[1][tid * 8]; u16* kd1b = &Kb[1][(tid + 256) * 8];
  u16* vd0a = &Vb[0][tid * 8]; u16* vd0b = &Vb[0][(tid + 256) * 8];
  u16* vd1a = &Vb[1][tid * 8]; u16* vd1b = &Vb[1][(tid + 256) * 8];

  // ================= pass 1: l = sum exp2(sacc), 4-deep prefetch =================
  float l_run = 0.f;
  ld_lds16(ks1, kd0a); ld_lds16(ks2, kd0b);
  ld_lds16(ks1 + 64 * AD, kd1a); ld_lds16(ks2 + 64 * AD, kd1b);
  ld_lds16(ks1 + 2 * 64 * AD, vd0a); ld_lds16(ks2 + 2 * 64 * AD, vd0b);
  for (int ch4 = 0; ch4 < SS / 64; ch4 += 4) {
#pragma unroll
    for (int u = 0; u < 4; u++) {
      int ch = ch4 + u;
      int slot = (u + 3) & 3;  // static under unroll
      u16* pa = slot == 0 ? kd0a : slot == 1 ? kd1a : slot == 2 ? vd0a : vd1a;
      u16* pb = slot == 0 ? kd0b : slot == 1 ? kd1b : slot == 2 ? vd0b : vd1b;
      if (ch + 3 < SS / 64) {
        ld_lds16(ks1 + (ch + 3) * 64 * AD, pa);
        ld_lds16(ks2 + (ch + 3) * 64 * AD, pb);
        WAITV(6);  // chunks ch..ch+3 in flight (2 each); oldest pair done
      } else if (ch == SS / 64 - 3) {
        WAITV(4);
      } else if (ch == SS / 64 - 2) {
        WAITV(2);
      } else {
        WAITV(0);
      }
      BAR();
      const u16* kb = u == 0 ? Kb[0] : u == 1 ? Kb[1] : u == 2 ? Vb[0] : Vb[1];
      f32x4 sacc[4] = {};
      __builtin_amdgcn_s_setprio(1);
#pragma unroll
      for (int mi = 0; mi < 4; mi++) {
        bf16x8 a0 = KFRAG(kb, mi * 16 + li, g);
        bf16x8 a1 = KFRAG(kb, mi * 16 + li, 4 + g);
        sacc[mi] = MFMA16(a0, bq0, sacc[mi]);
        sacc[mi] = MFMA16(a1, bq1, sacc[mi]);
      }
      __builtin_amdgcn_s_setprio(0);
#pragma unroll
      for (int c = 0; c < 4; c++)
#pragma unroll
        for (int r = 0; r < 4; r++) l_run += exp2f(sacc[c][r]);
      WAITL0();
      BAR();
    }
  }
  // merge l across the 4 g-lanes holding the same q=li
  l_run += __shfl_xor(l_run, 16);
  l_run += __shfl_xor(l_run, 32);
  float moff = log2f(l_run);  // p = exp2(sacc - moff) is normalized softmax

  // ================= pass 2: attn write (nt) + PV =================
  ld_lds16(ks1, kd0a); ld_lds16(ks2, kd0b);
  ld_lds16(vs1, vd0a); ld_lds16(vs2, vd0b);
  f32x4 accv[4] = {};
  float* arow = attn_out + ((long)hb * SS + q0 + li) * SS;
  for (int ch2 = 0; ch2 < SS / 64; ch2 += 2) {
#pragma unroll
    for (int u = 0; u < 2; u++) {
      int ch = ch2 + u;
      u16* kpa = u ? kd0a : kd1a; u16* kpb = u ? kd0b : kd1b;
      u16* vpa = u ? vd0a : vd1a; u16* vpb = u ? vd0b : vd1b;
      if (ch + 1 < SS / 64) {
        ld_lds16(ks1 + (ch + 1) * 64 * AD, kpa);
        ld_lds16(ks2 + (ch + 1) * 64 * AD, kpb);
        ld_lds16(vs1 + (ch + 1) * 64, vpa);
        ld_lds16(vs2 + (ch + 1) * 64, vpb);
        if (ch == 0) {
          WAITV(4);  // queue: [KV0(4), KV1(4)] -> KV0 done
        } else {
          WAITV(8);  // queue: [KVc(4), S_{c-1}(4), KVn(4)] -> KVc done; stores fly
        }
      } else {
        WAITV(4);  // queue: [S_{c-2}(4), KVc(4), S_{c-1}(4)] -> KVc done
      }
      BAR();
      const u16* kb = Kb[u];
      const u16* vb = Vb[u];
      f32x4 sacc[4] = {};
      __builtin_amdgcn_s_setprio(1);
#pragma unroll
      for (int mi = 0; mi < 4; mi++) {
        bf16x8 a0 = KFRAG(kb, mi * 16 + li, g);
        bf16x8 a1 = KFRAG(kb, mi * 16 + li, 4 + g);
        sacc[mi] = MFMA16(a0, bq0, sacc[mi]);
        sacc[mi] = MFMA16(a1, bq1, sacc[mi]);
      }
      __builtin_amdgcn_s_setprio(0);
      // p = exp2(sacc - moff): nt-write attn f32, pack bf16 for PV
      u32 pw[8];
#pragma unroll
      for (int c = 0; c < 4; c++) {
        f32x4 pv;
#pragma unroll
        for (int r = 0; r < 4; r++) pv[r] = exp2f(sacc[c][r] - moff);
        __builtin_nontemporal_store(pv, (f32x4*)(arow + ch * 64 + c * 16 + 4 * g));
        pw[2 * c] = (u32)f2bf(pv[0]) | ((u32)f2bf(pv[1]) << 16);
        pw[2 * c + 1] = (u32)f2bf(pv[2]) | ((u32)f2bf(pv[3]) << 16);
      }
      // PV: k-step kk covers lane's own k = {32kk+16cc+4g+r}; A-frag = own packed p.
#pragma unroll
      for (int kk = 0; kk < 2; kk++) {
        u32x4 aw = {pw[4 * kk], pw[4 * kk + 1], pw[4 * kk + 2], pw[4 * kk + 3]};
        bf16x8 ap = __builtin_bit_cast(bf16x8, aw);
#pragma unroll
        for (int et = 0; et < 4; et++) {
          int row = et * 16 + li;  // e-row of V^T tile
          u16x4 b0 = V64(vb, row, 4 * kk + (g >> 1), g & 1);
          u16x4 b1 = V64(vb, row, 4 * kk + 2 + (g >> 1), g & 1);
          u16x8 ub = {b0[0], b0[1], b0[2], b0[3], b1[0], b1[1], b1[2], b1[3]};
          bf16x8 bv = __builtin_bit_cast(bf16x8, ub);
          accv[et] = MFMA16(ap, bv, accv[et]);
        }
      }
      WAITL0();
      BAR();
    }
  }

  // epilogue: att already normalized; lane(g,li) holds att[q=4g+r][e=et*16+li]
#pragma unroll
  for (int et = 0; et < 4; et++)
#pragma unroll
    for (int r = 0; r < 4; r++)
      cat[((long)b * SS + q0 + 4 * g + r) * DM + h * AD + et * 16 + li] = f2bf(accv[et][r]);
}

extern "C" void kernel_launch(void* const* d_in, const int* in_sizes, int n_in, void* d_out,
                              int out_size, void* d_ws, size_t ws_size, hipStream_t stream) {
  const float* q = (const float*)d_in[0];
  const float* k = (const float*)d_in[1];
  const float* v = (const float*)d_in[2];
  const float* Wq = (const float*)d_in[3];
  const float* Wk = (const float*)d_in[4];
  const float* Wv = (const float*)d_in[5];
  const float* Wo = (const float*)d_in[6];
  float* out = (float*)d_out;
  float* attn_out = out + (long)BB * SS * DM;

  const long NX = (long)BB * SS * DM;  // 4,194,304
  const long NW = (long)NH * DM * AD;  // 1,048,576
  u16* ws = (u16*)d_ws;
  u16* xq = ws;        // xq, xk, xv contiguous (qkvproj relies on this)
  u16* xk = xq + NX;
  u16* xv = xk + NX;
  u16* WqT = xv + NX;  // WqT, WkT, WvT contiguous (tcast MODE 1 + qkvproj rely on this)
  u16* WkT = WqT + NW;
  u16* WvT = WkT + NW;
  u16* WoT = WvT + NW;
  u16* qhw = WoT + (long)DM * DM;  // qhw, khw, vhw contiguous (qkvproj relies on this)
  u16* khw = qhw + NX;
  u16* vhw = khw + NX;
  u16* catw = vhw + NX;  // total ws use: 64 MiB

  (void)xk; (void)xv; (void)WkT; (void)WvT;

  cast3_kernel<<<dim3(700, 3), 256, 0, stream>>>(q, k, v, xq, xk, xv, (int)(NX / 8));
  // fold log2e/ATT_DIM into WqT (sacc in log2 units)
  tcast_kernel<1><<<dim3(16, 1, 48), 256, 0, stream>>>(Wq, Wk, Wv, WqT, DM, AD, LOG2E / AD);
  tcast_kernel<0><<<dim3(16, 16, 1), 256, 0, stream>>>(Wo, nullptr, nullptr, WoT, DM, DM, 1.0f);

  // merged Q/K/V projections: grid 32 x 16 x 3 = 1536 blocks
  qkvproj_kernel<<<dim3(BB * SS / 128, NH, 3), 256, 0, stream>>>(xq, WqT, qhw);

  // attention: grid 32 x 16 x 2 = 1024 blocks of 256 thr
  attn_kernel<<<dim3(SS / 64, NH, BB), 256, 0, stream>>>(qhw, khw, vhw, attn_out, catw);

  // out[b][s][d] = cat @ Wo : grid 32 x 16 = 512 blocks
  outproj_kernel<<<dim3(BB * SS / 128, DM / 64), 256, 0, stream>>>(catw, WoT, out);
}